// Round 4
// baseline (202.400 us; speedup 1.0000x reference)
//
#include <hip/hip_runtime.h>

// B=64, L=512, D=768, V=100
// summed[b,l,:] = w0s * pooler[b,l,:] + w1s * xt[b,:]
//   xt[b,d] = e0*W[0,d] + e1*W[1,d] + b_dense[d],  (e0,e1) = emb_table[ids[b]]
//   s00 = p.p (row), s01 = p.xt (row), s11 = xt.xt (per b); S0 = sum p, S1 = sum xt
//   out = ((w0s*p + w1s*xt) - mean)*rstd*gamma + beta
//       = gamma*(a*p + (c*xt - m)) + beta,  a=w0s*rstd, c=w1s*rstd, m=mean*rstd
//
// R3/R4/R5 lesson: any single-kernel form has the chain
//   load tile -> butterfly -> exp -> use tile again
// and hipcc's pressure-minimizing scheduler refuses to keep the 48-VGPR tile
// live across it (VGPR_Count stuck at 64 even with launch_bounds(256,4)).
// All variants: 57-66us, VALUBusy ~15%, HBM ~30%, lockstep latency-bound.
//
// R6: TWO STREAMING PASSES via d_ws (512 KB = 32768 rows x float4{a,c,m,0}).
//   pass1: pooler read -> per-row (s00,s01,S0) partials consumed IMMEDIATELY
//          (no long-lived tile) -> 14-chain butterfly -> per-lane softmax/LN
//          scalars (lanes 0-3 own one row each via cndmask selects, no
//          runtime array indexing -> no scratch) -> 16B store per row.
//   pass2: pure triad, no reduction: p load + 24 FMA + NT store. Pooler
//          re-read is L3-hot (streamed by pass1 moments earlier).

constexpr int Bc = 64;
constexpr int Lc = 512;
constexpr int Dc = 768;            // 192 float4 = 3 float4 per lane (wave64)
constexpr float LN_EPS = 1e-6f;
constexpr int WPB = 4;             // waves per block
constexpr int RPW = 4;             // rows per wave (4 | 512 -> same b per wave)
constexpr int RPB = WPB * RPW;     // 16 rows per block

typedef float nv_float4 __attribute__((ext_vector_type(4)));

__global__ __launch_bounds__(64 * WPB) void pass1_scalars(
    const int*   __restrict__ ids,        // (B,1)
    const float* __restrict__ pooler,     // (B,L,D)
    const float* __restrict__ emb_table,  // (V,2)
    const float* __restrict__ W,          // (2,D)
    const float* __restrict__ bvec,       // (D,)
    float4*      __restrict__ ws)         // (B*L) x {a,c,m,0}
{
    const int wave = threadIdx.x >> 6;
    const int lane = threadIdx.x & 63;
    const int row0 = blockIdx.x * RPB + wave * RPW;
    const int b    = row0 >> 9;           // L = 512

    const float4* W0_4 = (const float4*)W;
    const float4* W1_4 = (const float4*)(W + Dc);
    const float4* b_4  = (const float4*)bvec;

    const int id = ids[b];
    const float e0 = emb_table[id * 2 + 0];
    const float e1 = emb_table[id * 2 + 1];

    // xt (per-b, broadcast L1/L2-hot loads) + s11/S1 partials
    float4 xt[3];
    float s11 = 0.f, S1 = 0.f;
#pragma unroll
    for (int j = 0; j < 3; ++j) {
        const int i4 = lane + j * 64;
        float4 w0 = W0_4[i4], w1 = W1_4[i4], bd = b_4[i4];
        float4 x;
        x.x = fmaf(e0, w0.x, fmaf(e1, w1.x, bd.x));
        x.y = fmaf(e0, w0.y, fmaf(e1, w1.y, bd.y));
        x.z = fmaf(e0, w0.z, fmaf(e1, w1.z, bd.z));
        x.w = fmaf(e0, w0.w, fmaf(e1, w1.w, bd.w));
        xt[j] = x;
        s11 += x.x*x.x + x.y*x.y + x.z*x.z + x.w*x.w;
        S1  += x.x + x.y + x.z + x.w;
    }

    // Per-row partials: pooler value consumed immediately (short lifetime ->
    // compiler can pipeline rows without holding tiles).
    const float4* p_base = (const float4*)(pooler + (size_t)row0 * Dc);
    float s00[RPW], s01[RPW], S0[RPW];
#pragma unroll
    for (int r = 0; r < RPW; ++r) {
        float a0 = 0.f, a1 = 0.f, a2 = 0.f;
#pragma unroll
        for (int j = 0; j < 3; ++j) {
            const float4 p = p_base[r * (Dc / 4) + lane + j * 64];
            a0 += p.x*p.x + p.y*p.y + p.z*p.z + p.w*p.w;
            a1 += p.x*xt[j].x + p.y*xt[j].y + p.z*xt[j].z + p.w*xt[j].w;
            a2 += p.x + p.y + p.z + p.w;
        }
        s00[r] = a0; s01[r] = a1; S0[r] = a2;
    }

    // Joint butterfly: 6 steps, 14 interleaved chains
#pragma unroll
    for (int off = 32; off > 0; off >>= 1) {
        s11 += __shfl_xor(s11, off);
        S1  += __shfl_xor(S1,  off);
#pragma unroll
        for (int r = 0; r < RPW; ++r) {
            s00[r] += __shfl_xor(s00[r], off);
            s01[r] += __shfl_xor(s01[r], off);
            S0[r]  += __shfl_xor(S0[r],  off);
        }
    }

    // Lanes 0-3 each own one row; select via cndmask (compile-time indices
    // only -> no scratch). All lanes compute; lanes 0-3 store.
    const int r = lane & 3;
    const float t00 = (r & 1) ? s00[1] : s00[0];
    const float u00 = (r & 1) ? s00[3] : s00[2];
    const float v00 = (r & 2) ? u00 : t00;
    const float t01 = (r & 1) ? s01[1] : s01[0];
    const float u01 = (r & 1) ? s01[3] : s01[2];
    const float v01 = (r & 2) ? u01 : t01;
    const float tS0 = (r & 1) ? S0[1] : S0[0];
    const float uS0 = (r & 1) ? S0[3] : S0[2];
    const float vS0 = (r & 2) ? uS0 : tS0;

    // Two 2-way softmaxes (max-subtracted: s00 ~ O(768), naive exp overflows).
    const float m0  = fmaxf(v00, v01);
    const float a00 = __expf(v00 - m0);
    const float a01 = __expf(v01 - m0);
    const float r0  = 1.f / (a00 + a01);
    const float m1  = fmaxf(v01, s11);
    const float a10 = __expf(v01 - m1);
    const float a11 = __expf(s11 - m1);
    const float r1  = 1.f / (a10 + a11);
    const float w0s = a00 * r0 + a10 * r1;   // weight on pooler
    const float w1s = a01 * r0 + a11 * r1;   // weight on xt

    const float invD = 1.f / (float)Dc;
    const float mean = (w0s * vS0 + w1s * S1) * invD;
    const float ex2  = (w0s*w0s*v00 + 2.f*w0s*w1s*v01 + w1s*w1s*s11) * invD;
    const float var  = ex2 - mean * mean;
    const float rstd = rsqrtf(var + LN_EPS);

    if (lane < 4) {
        float4 o;
        o.x = w0s * rstd;      // a
        o.y = w1s * rstd;      // c
        o.z = mean * rstd;     // m
        o.w = 0.f;
        ws[row0 + r] = o;      // lanes 0-3 -> 4 consecutive 16B stores
    }
}

__global__ __launch_bounds__(64 * WPB) void pass2_apply(
    const int*   __restrict__ ids,
    const float* __restrict__ pooler,
    const float* __restrict__ emb_table,
    const float* __restrict__ W,
    const float* __restrict__ bvec,
    const float* __restrict__ gamma,
    const float* __restrict__ beta,
    const float4* __restrict__ ws,
    float*       __restrict__ out)
{
    const int wave = threadIdx.x >> 6;
    const int lane = threadIdx.x & 63;
    const int row0 = blockIdx.x * RPB + wave * RPW;
    const int b    = row0 >> 9;

    const float4* W0_4 = (const float4*)W;
    const float4* W1_4 = (const float4*)(W + Dc);
    const float4* b_4  = (const float4*)bvec;
    const float4* g_4  = (const float4*)gamma;
    const float4* be_4 = (const float4*)beta;

    const int id = ids[b];
    const float e0 = emb_table[id * 2 + 0];
    const float e1 = emb_table[id * 2 + 1];

    // Per-wave invariants (broadcast, cache-hot): xt, gamma, beta
    float4 xt[3], gm[3], bt[3];
#pragma unroll
    for (int j = 0; j < 3; ++j) {
        const int i4 = lane + j * 64;
        float4 w0 = W0_4[i4], w1 = W1_4[i4], bd = b_4[i4];
        gm[j] = g_4[i4];
        bt[j] = be_4[i4];
        float4 x;
        x.x = fmaf(e0, w0.x, fmaf(e1, w1.x, bd.x));
        x.y = fmaf(e0, w0.y, fmaf(e1, w1.y, bd.y));
        x.z = fmaf(e0, w0.z, fmaf(e1, w1.z, bd.z));
        x.w = fmaf(e0, w0.w, fmaf(e1, w1.w, bd.w));
        xt[j] = x;
    }

    // Per-row scalars up front (4 independent uniform 16B loads)
    float4 s[RPW];
#pragma unroll
    for (int r = 0; r < RPW; ++r) s[r] = ws[row0 + r];

    const float4* p_base = (const float4*)(pooler + (size_t)row0 * Dc);
    nv_float4*    o_base = (nv_float4*)(out + (size_t)row0 * Dc);

    // Pure triad per row: 3 loads + 24 FMA + 3 NT stores, no reduction,
    // no cross-row dependence -> freely pipelineable.
#pragma unroll
    for (int rr = 0; rr < RPW; ++rr) {
        const float a = s[rr].x, c = s[rr].y, m = s[rr].z;
        const float4* prow = p_base + (size_t)rr * (Dc / 4);
        nv_float4*    orow = o_base + (size_t)rr * (Dc / 4);
#pragma unroll
        for (int j = 0; j < 3; ++j) {
            const float4 p = prow[lane + j * 64];
            nv_float4 o;
            o.x = fmaf(gm[j].x, fmaf(a, p.x, fmaf(c, xt[j].x, -m)), bt[j].x);
            o.y = fmaf(gm[j].y, fmaf(a, p.y, fmaf(c, xt[j].y, -m)), bt[j].y);
            o.z = fmaf(gm[j].z, fmaf(a, p.z, fmaf(c, xt[j].z, -m)), bt[j].z);
            o.w = fmaf(gm[j].w, fmaf(a, p.w, fmaf(c, xt[j].w, -m)), bt[j].w);
            __builtin_nontemporal_store(o, &orow[lane + j * 64]);
        }
    }
}

extern "C" void kernel_launch(void* const* d_in, const int* in_sizes, int n_in,
                              void* d_out, int out_size, void* d_ws, size_t ws_size,
                              hipStream_t stream) {
    const int*   ids       = (const int*)  d_in[0];
    const float* pooler    = (const float*)d_in[1];
    const float* emb_table = (const float*)d_in[2];
    const float* W_dense   = (const float*)d_in[3];
    const float* b_dense   = (const float*)d_in[4];
    const float* gamma     = (const float*)d_in[5];
    const float* beta      = (const float*)d_in[6];
    float* out = (float*)d_out;
    float4* ws = (float4*)d_ws;           // needs 32768 * 16 B = 512 KB

    const int nrows  = Bc * Lc;           // 32768
    const int nblk   = nrows / RPB;       // 2048

    hipLaunchKernelGGL(pass1_scalars, dim3(nblk), dim3(64 * WPB), 0, stream,
                       ids, pooler, emb_table, W_dense, b_dense, ws);
    hipLaunchKernelGGL(pass2_apply, dim3(nblk), dim3(64 * WPB), 0, stream,
                       ids, pooler, emb_table, W_dense, b_dense, gamma, beta,
                       ws, out);
}

// Round 5
// 187.302 us; speedup vs baseline: 1.0806x; 1.0806x over previous
//
#include <hip/hip_runtime.h>

// B=64, L=512, D=768, V=100
// summed[b,l,:] = w0s * pooler[b,l,:] + w1s * xt[b,:]
//   xt[b,d] = e0*W[0,d] + e1*W[1,d] + b_dense[d],  (e0,e1) = emb_table[ids[b]]
//   s00 = p.p (row), s01 = p.xt (row), s11 = xt.xt (per b); S0 = sum p, S1 = sum xt
//   out = gamma*(a*p + (c*xt - m)) + beta,  a=w0s*rstd, c=w1s*rstd, m=mean*rstd
//
// History:
// R1/R2: 4-wave blocks + NT stores.                           (~62 us kernel)
// R3: 4 rows/wave hoisting — REGRESSED, serialized row loop.  (~65 us)
// R4/R5: loads-up-front + launch_bounds(256,4) — NEUTRAL. VGPR stuck at 64:
//   hipcc SINKS/REMATERIALIZES loads rather than hold a 48-VGPR tile across
//   the butterfly+exp serialization point. Waves drain; ~20 us avg lifetime
//   for ~1 us of issue work (occupancy 32% w/ 8192 waves over 62 us).
// R6: two-pass via d_ws — REGRESSED (~71 us): +66% traffic, same lockstep.
// Fill kernels prove the target: 9% occupancy, 4.7% VALU, 6.8 TB/s —
//   fire-and-forget memory ops, no pipeline drain.
// R7: decouple p's second use via LDS. load -> ds_write + partial FMA: the
//   loaded value DIES immediately (no long lifetime -> scheduler keeps all
//   6 loads/wave in flight). Epilogue reads own-wave LDS slice (no barrier,
//   no vmcnt). 24 KB/block -> 6 blocks/CU -> 24 waves/CU, 144 KB/CU in flight.

constexpr int Bc = 64;
constexpr int Lc = 512;
constexpr int Dc = 768;            // 192 float4 = 3 float4 per lane (wave64)
constexpr int NF4 = Dc / 4;        // 192
constexpr float LN_EPS = 1e-6f;
constexpr int WPB = 4;             // waves per block
constexpr int RPW = 2;             // rows per wave (2 | 512 -> same b per wave)
constexpr int RPB = WPB * RPW;     // 8 rows per block

typedef float nv_float4 __attribute__((ext_vector_type(4)));

__global__ __launch_bounds__(64 * WPB) void hier_attn_ln_kernel(
    const int*   __restrict__ ids,        // (B,1)
    const float* __restrict__ pooler,     // (B,L,D)
    const float* __restrict__ emb_table,  // (V,2)
    const float* __restrict__ W,          // (2,D)
    const float* __restrict__ bvec,       // (D,)
    const float* __restrict__ gamma,      // (D,)
    const float* __restrict__ beta,       // (D,)
    float*       __restrict__ out)        // (B,L,D)
{
    // Per-wave private slices; written and read by the same wave only ->
    // no __syncthreads anywhere (no inter-wave lockstep).
    __shared__ float4 tile[WPB][RPW][NF4];          // 4*2*192*16 B = 24 KB

    const int wave = threadIdx.x >> 6;
    const int lane = threadIdx.x & 63;
    const int row0 = blockIdx.x * RPB + wave * RPW;
    const int b    = row0 >> 9;                     // L = 512; 8 | 512

    const float4* W0_4 = (const float4*)W;
    const float4* W1_4 = (const float4*)(W + Dc);
    const float4* b_4  = (const float4*)bvec;
    const float4* g_4  = (const float4*)gamma;
    const float4* be_4 = (const float4*)beta;

    const int id = ids[b];
    const float e0 = emb_table[id * 2 + 0];
    const float e1 = emb_table[id * 2 + 1];

    // ---- xt (broadcast cache-hot loads) + per-b partials ----
    float4 xt[3];
    float s11 = 0.f, S1 = 0.f;
#pragma unroll
    for (int j = 0; j < 3; ++j) {
        const int i4 = lane + j * 64;
        float4 w0 = W0_4[i4], w1 = W1_4[i4], bd = b_4[i4];
        float4 x;
        x.x = fmaf(e0, w0.x, fmaf(e1, w1.x, bd.x));
        x.y = fmaf(e0, w0.y, fmaf(e1, w1.y, bd.y));
        x.z = fmaf(e0, w0.z, fmaf(e1, w1.z, bd.z));
        x.w = fmaf(e0, w0.w, fmaf(e1, w1.w, bd.w));
        xt[j] = x;
        s11 += x.x*x.x + x.y*x.y + x.z*x.z + x.w*x.w;
        S1  += x.x + x.y + x.z + x.w;
    }

    // ---- pooler loads: consumed IMMEDIATELY (ds_write + 3 FMAs), value dies.
    //      Scheduler is free to keep all 6 loads in flight. ----
    const float4* p_base = (const float4*)(pooler + (size_t)row0 * Dc);
    float s00[RPW], s01[RPW], S0[RPW];
#pragma unroll
    for (int r = 0; r < RPW; ++r) {
        float a0 = 0.f, a1 = 0.f, a2 = 0.f;
#pragma unroll
        for (int j = 0; j < 3; ++j) {
            const int i4 = lane + j * 64;
            const float4 p = p_base[r * NF4 + i4];
            tile[wave][r][i4] = p;                   // ds_write_b128, own slice
            a0 += p.x*p.x + p.y*p.y + p.z*p.z + p.w*p.w;
            a1 += p.x*xt[j].x + p.y*xt[j].y + p.z*xt[j].z + p.w*xt[j].w;
            a2 += p.x + p.y + p.z + p.w;
        }
        s00[r] = a0; s01[r] = a1; S0[r] = a2;
    }

    // ---- joint butterfly: 6 steps, 8 interleaved chains ----
#pragma unroll
    for (int off = 32; off > 0; off >>= 1) {
        s11 += __shfl_xor(s11, off);
        S1  += __shfl_xor(S1,  off);
#pragma unroll
        for (int r = 0; r < RPW; ++r) {
            s00[r] += __shfl_xor(s00[r], off);
            s01[r] += __shfl_xor(s01[r], off);
            S0[r]  += __shfl_xor(S0[r],  off);
        }
    }

    // ---- gamma/beta (cache-hot broadcast), latency hidden under softmax ----
    float4 gm[3], bt[3];
#pragma unroll
    for (int j = 0; j < 3; ++j) {
        gm[j] = g_4[lane + j * 64];
        bt[j] = be_4[lane + j * 64];
    }

    // ---- per-row softmax + LN scalars (static indices only) ----
    const float invD = 1.f / (float)Dc;
    float ascale[RPW], cscale[RPW], mshift[RPW];
#pragma unroll
    for (int r = 0; r < RPW; ++r) {
        // Two 2-way softmaxes (max-subtracted: s00 ~ O(768), naive exp overflows).
        const float m0  = fmaxf(s00[r], s01[r]);
        const float a00 = __expf(s00[r] - m0);
        const float a01 = __expf(s01[r] - m0);
        const float r0  = 1.f / (a00 + a01);
        const float m1  = fmaxf(s01[r], s11);
        const float a10 = __expf(s01[r] - m1);
        const float a11 = __expf(s11 - m1);
        const float r1  = 1.f / (a10 + a11);
        const float w0s = a00 * r0 + a10 * r1;       // weight on pooler
        const float w1s = a01 * r0 + a11 * r1;       // weight on xt

        const float mean = (w0s * S0[r] + w1s * S1) * invD;
        const float ex2  = (w0s*w0s*s00[r] + 2.f*w0s*w1s*s01[r] + w1s*w1s*s11) * invD;
        const float var  = ex2 - mean * mean;
        const float rstd = rsqrtf(var + LN_EPS);

        ascale[r] = w0s * rstd;
        cscale[r] = w1s * rstd;
        mshift[r] = mean * rstd;
    }

    // ---- epilogue: re-read p from own LDS slice (ds_read_b128, ~120 cyc,
    //      pipelined, no vmcnt), triad, NT store ----
    nv_float4* o_base = (nv_float4*)(out + (size_t)row0 * Dc);
#pragma unroll
    for (int r = 0; r < RPW; ++r) {
        const float a = ascale[r], c = cscale[r], m = mshift[r];
        nv_float4* orow = o_base + (size_t)r * NF4;
#pragma unroll
        for (int j = 0; j < 3; ++j) {
            const int i4 = lane + j * 64;
            const float4 p = tile[wave][r][i4];
            nv_float4 o;
            o.x = fmaf(gm[j].x, fmaf(a, p.x, fmaf(c, xt[j].x, -m)), bt[j].x);
            o.y = fmaf(gm[j].y, fmaf(a, p.y, fmaf(c, xt[j].y, -m)), bt[j].y);
            o.z = fmaf(gm[j].z, fmaf(a, p.z, fmaf(c, xt[j].z, -m)), bt[j].z);
            o.w = fmaf(gm[j].w, fmaf(a, p.w, fmaf(c, xt[j].w, -m)), bt[j].w);
            __builtin_nontemporal_store(o, &orow[i4]);
        }
    }
}

extern "C" void kernel_launch(void* const* d_in, const int* in_sizes, int n_in,
                              void* d_out, int out_size, void* d_ws, size_t ws_size,
                              hipStream_t stream) {
    const int*   ids       = (const int*)  d_in[0];
    const float* pooler    = (const float*)d_in[1];
    const float* emb_table = (const float*)d_in[2];
    const float* W_dense   = (const float*)d_in[3];
    const float* b_dense   = (const float*)d_in[4];
    const float* gamma     = (const float*)d_in[5];
    const float* beta      = (const float*)d_in[6];
    float* out = (float*)d_out;

    const int nrows = Bc * Lc;                      // 32768
    hipLaunchKernelGGL(hier_attn_ln_kernel,
                       dim3(nrows / RPB), dim3(64 * WPB),   // 4096 blocks
                       0, stream,
                       ids, pooler, emb_table, W_dense, b_dense, gamma, beta, out);
}